// Round 7
// baseline (189.074 us; speedup 1.0000x reference)
//
#include <hip/hip_runtime.h>
#include <math.h>

// Problem constants: B=4, L=2048, d=192, n=64, chunk=128
#define TOK      8192
#define DIM      192
#define NST      64
#define PCHUNK   128
#define NCHUNKS  64
#define CPB      16
#define BATCH    4
#define SUB      32
#define NSUB     4
#define NG       2      // n-groups
#define NPG      32     // n per group

typedef __attribute__((ext_vector_type(8))) short  bf16x8;
typedef __attribute__((ext_vector_type(4))) float  f32x4;

__device__ __forceinline__ unsigned short f2bf(float f) {
    unsigned int u = __float_as_uint(f);
    u += 0x7fff + ((u >> 16) & 1);          // RNE
    return (unsigned short)(u >> 16);
}
__device__ __forceinline__ float bf2f(unsigned short h) {
    return __uint_as_float(((unsigned int)h) << 16);
}

// ---------------------------------------------------------------------------
// Prep: cast x / W_xp / W_out to bf16; build Wcomb = [W_B;W_C;W_dt] @ W_xp_top
// (fp32 accumulate -> bf16) and folded bias biasC[n] = Wrow.b_xp (+ b_dt).
// ---------------------------------------------------------------------------
#define XU      393216                 // TOK*DIM/4
#define WXPU    18432                  // 384*192/4
#define WOUTU   9216                   // 192*192/4
#define CAST_U  (XU + WXPU + WOUTU)
#define WCOMB_N 61440                  // 320*192
#define PREP_N  (CAST_U + WCOMB_N + 320)

__global__ __launch_bounds__(256)
void prep_kernel(const float* __restrict__ x,   const float* __restrict__ Wxp,
                 const float* __restrict__ WB,  const float* __restrict__ WC,
                 const float* __restrict__ Wdt, const float* __restrict__ Wout,
                 const float* __restrict__ b_xp, const float* __restrict__ b_dt,
                 unsigned short* __restrict__ xb,     unsigned short* __restrict__ wxpb,
                 unsigned short* __restrict__ woutb,  unsigned short* __restrict__ wcombb,
                 float* __restrict__ biasC)
{
    int u = blockIdx.x * 256 + threadIdx.x;
    if (u < CAST_U) {
        const float* src; unsigned short* dst; int idx;
        if      (u < XU)          { src = x;    dst = xb;    idx = u; }
        else if (u < XU + WXPU)   { src = Wxp;  dst = wxpb;  idx = u - XU; }
        else                      { src = Wout; dst = woutb; idx = u - XU - WXPU; }
        float4 v = *(const float4*)(src + (size_t)idx * 4);
        ushort4 r; r.x = f2bf(v.x); r.y = f2bf(v.y); r.z = f2bf(v.z); r.w = f2bf(v.w);
        *(ushort4*)(dst + (size_t)idx * 4) = r;
    } else if (u < CAST_U + WCOMB_N) {
        int idx = u - CAST_U;
        int n = idx / DIM, k = idx % DIM;
        const float* wr = (n < 64) ? WB + (size_t)n * DIM
                        : (n < 128) ? WC + (size_t)(n - 64) * DIM
                                    : Wdt + (size_t)(n - 128) * DIM;
        float acc = 0.f;
        for (int j = 0; j < DIM; ++j)
            acc = fmaf(wr[j], Wxp[(size_t)j * DIM + k], acc);
        wcombb[(size_t)n * DIM + k] = f2bf(acc);
    } else if (u < PREP_N) {
        int n = u - CAST_U - WCOMB_N;
        const float* wr = (n < 64) ? WB + (size_t)n * DIM
                        : (n < 128) ? WC + (size_t)(n - 64) * DIM
                                    : Wdt + (size_t)(n - 128) * DIM;
        float acc = 0.f;
        for (int j = 0; j < DIM; ++j)
            acc = fmaf(wr[j], b_xp[j], acc);
        if (n >= 128) acc += b_dt[n - 128];
        biasC[n] = acc;
    }
}

// ---------------------------------------------------------------------------
// MFMA wave-tile: 64x64 of X[M,K] @ W[N,K]^T (bf16 -> fp32)
// ---------------------------------------------------------------------------
__device__ __forceinline__
void mfma_64x64(const unsigned short* __restrict__ X, int ldx,
                const unsigned short* __restrict__ W, int K,
                int m_wave, int n0, int lr, int kg, f32x4 acc[4][4])
{
    for (int k0 = 0; k0 < K; k0 += 32) {
        bf16x8 af[4], bfr[4];
        #pragma unroll
        for (int mi = 0; mi < 4; ++mi)
            af[mi] = *(const bf16x8*)(X + (size_t)(m_wave + mi*16 + lr) * ldx + k0 + kg*8);
        #pragma unroll
        for (int ni = 0; ni < 4; ++ni)
            bfr[ni] = *(const bf16x8*)(W + (size_t)(n0 + ni*16 + lr) * K + k0 + kg*8);
        #pragma unroll
        for (int mi = 0; mi < 4; ++mi)
            #pragma unroll
            for (int ni = 0; ni < 4; ++ni)
                acc[mi][ni] = __builtin_amdgcn_mfma_f32_16x16x32_bf16(
                                  af[mi], bfr[ni], acc[mi][ni], 0, 0, 0);
    }
}

// x @ W_xp^T + b_xp -> xbar fp32 [TOK][192] | zarr fp32 [TOK][192]
__global__ __launch_bounds__(256)
void xz_gemm(const unsigned short* __restrict__ xb,
             const unsigned short* __restrict__ wxpb,
             const float* __restrict__ b_xp,
             float* __restrict__ xbar, float* __restrict__ zarr)
{
    const int lane = threadIdx.x & 63, wave = threadIdx.x >> 6;
    const int m_wave = blockIdx.x * 256 + wave * 64;
    const int n0 = blockIdx.y * 64;
    const int lr = lane & 15, kg = lane >> 4;
    f32x4 acc[4][4] = {};
    mfma_64x64(xb, DIM, wxpb, DIM, m_wave, n0, lr, kg, acc);
    float* dst = (n0 < DIM) ? xbar : zarr;
    int cofs = (n0 < DIM) ? 0 : DIM;
    #pragma unroll
    for (int ni = 0; ni < 4; ++ni) {
        int col = n0 + ni*16 + lr;
        float bias = b_xp[col];
        #pragma unroll
        for (int mi = 0; mi < 4; ++mi)
            #pragma unroll
            for (int r = 0; r < 4; ++r) {
                int row = m_wave + mi*16 + kg*4 + r;
                dst[(size_t)row * DIM + col - cofs] = acc[mi][ni][r] + bias;
            }
    }
}

// x @ Wcomb^T + biasC: cols<128 -> BC fp32 [TOK][128]; cols>=128 -> Abar
__global__ __launch_bounds__(256)
void bcdt_gemm(const unsigned short* __restrict__ xb,
               const unsigned short* __restrict__ wcombb,
               const float* __restrict__ biasC, const float* __restrict__ A_log,
               float* __restrict__ BC, float* __restrict__ Abar)
{
    const int lane = threadIdx.x & 63, wave = threadIdx.x >> 6;
    const int m_wave = blockIdx.x * 256 + wave * 64;
    const int n0 = blockIdx.y * 64;
    const int lr = lane & 15, kg = lane >> 4;
    f32x4 acc[4][4] = {};
    mfma_64x64(xb, DIM, wcombb, DIM, m_wave, n0, lr, kg, acc);
    if (n0 < 128) {
        #pragma unroll
        for (int ni = 0; ni < 4; ++ni) {
            int col = n0 + ni*16 + lr;
            float bias = biasC[col];
            #pragma unroll
            for (int mi = 0; mi < 4; ++mi)
                #pragma unroll
                for (int r = 0; r < 4; ++r) {
                    int row = m_wave + mi*16 + kg*4 + r;
                    BC[(size_t)row * 128 + col] = acc[mi][ni][r] + bias;
                }
        }
    } else {
        #pragma unroll
        for (int ni = 0; ni < 4; ++ni) {
            int col = n0 + ni*16 + lr;
            int c2 = col - 128;
            float bias = biasC[col];
            float Av = -expf(A_log[c2]);
            #pragma unroll
            for (int mi = 0; mi < 4; ++mi)
                #pragma unroll
                for (int r = 0; r < 4; ++r) {
                    int row = m_wave + mi*16 + kg*4 + r;
                    float v = acc[mi][ni][r] + bias;
                    float sp = (v > 20.f) ? v : log1pf(expf(v));
                    Abar[(size_t)row * DIM + c2] = expf(sp * Av);
                }
        }
    }
}

// out = y_g @ W_out^T + b_out  (fp32)
__global__ __launch_bounds__(256)
void out_gemm(const unsigned short* __restrict__ ygb,
              const unsigned short* __restrict__ woutb,
              const float* __restrict__ b_out, float* __restrict__ out)
{
    const int lane = threadIdx.x & 63, wave = threadIdx.x >> 6;
    const int m_wave = blockIdx.x * 256 + wave * 64;
    const int n0 = blockIdx.y * 64;
    const int lr = lane & 15, kg = lane >> 4;
    f32x4 acc[4][4] = {};
    mfma_64x64(ygb, DIM, woutb, DIM, m_wave, n0, lr, kg, acc);
    #pragma unroll
    for (int ni = 0; ni < 4; ++ni) {
        int col = n0 + ni*16 + lr;
        float bias = b_out[col];
        #pragma unroll
        for (int mi = 0; mi < 4; ++mi)
            #pragma unroll
            for (int r = 0; r < 4; ++r) {
                int row = m_wave + mi*16 + kg*4 + r;
                out[(size_t)row * DIM + col] = acc[mi][ni][r] + bias;
            }
    }
}

// ---------------------------------------------------------------------------
// Fused sub-state + chunk-state partial. Grid (64, 4 subs, 2 g), 192 thr.
// ---------------------------------------------------------------------------
__global__ __launch_bounds__(192)
void state_kernel(const float* __restrict__ xbar,
                  const float* __restrict__ Abar,
                  const float* __restrict__ Bm,      // stride 128
                  float* __restrict__ S,
                  float* __restrict__ R,
                  float* __restrict__ dprod)
{
    int bc = blockIdx.x, s = blockIdx.y, g = blockIdx.z;
    int dd = threadIdx.x;
    int t0 = bc * PCHUNK + s * SUB;
    __shared__ float Bs[SUB][NPG];
    for (int q = threadIdx.x; q < SUB * NPG / 4; q += 192) {
        int row = q >> 3, c4 = q & 7;
        *(float4*)&Bs[row][c4 * 4] =
            *(const float4*)(Bm + (size_t)(t0 + row) * 128 + g * NPG + c4 * 4);
    }
    __syncthreads();
    float H[NPG] = {}, Rr[NPG] = {};
    float cp = 1.f;
    float a_cur = Abar[(size_t)t0 * DIM + dd] + 1e-8f;
    float x_cur = xbar[(size_t)t0 * DIM + dd];
    for (int i = 0; i < SUB; ++i) {
        float a_nxt = 0.f, x_nxt = 0.f;
        if (i + 1 < SUB) {
            a_nxt = Abar[(size_t)(t0 + i + 1) * DIM + dd] + 1e-8f;
            x_nxt = xbar[(size_t)(t0 + i + 1) * DIM + dd];
        }
        cp *= a_cur;
        #pragma unroll
        for (int q = 0; q < NPG / 4; ++q) {
            float4 b = *(const float4*)&Bs[i][q * 4];
            float u0 = b.x * x_cur, u1 = b.y * x_cur, u2 = b.z * x_cur, u3 = b.w * x_cur;
            H[q*4+0] = fmaf(a_cur, H[q*4+0], u0); Rr[q*4+0] = fmaf(u0, a_cur, Rr[q*4+0]);
            H[q*4+1] = fmaf(a_cur, H[q*4+1], u1); Rr[q*4+1] = fmaf(u1, a_cur, Rr[q*4+1]);
            H[q*4+2] = fmaf(a_cur, H[q*4+2], u2); Rr[q*4+2] = fmaf(u2, a_cur, Rr[q*4+2]);
            H[q*4+3] = fmaf(a_cur, H[q*4+3], u3); Rr[q*4+3] = fmaf(u3, a_cur, Rr[q*4+3]);
        }
        a_cur = a_nxt; x_cur = x_nxt;
    }
    size_t base = (((size_t)(bc * NSUB + s)) * NST + g * NPG) * DIM + dd;
    #pragma unroll
    for (int j = 0; j < NPG; ++j) {
        S[base + (size_t)j * DIM] = H[j];
        R[base + (size_t)j * DIM] = Rr[j];
    }
    if (g == 0) dprod[(size_t)(bc * NSUB + s) * DIM + dd] = cp;
}

// ---------------------------------------------------------------------------
// Per-chunk reductions: cA[bc,dd] = prod_s dprod ; Rsum[bc,nn,dd] = sum_s R
// ---------------------------------------------------------------------------
__global__ __launch_bounds__(256)
void reduce_kernel(const float* __restrict__ dprod,
                   const float* __restrict__ R,
                   float* __restrict__ cA,
                   float* __restrict__ Rsum)
{
    int u = blockIdx.x * 256 + threadIdx.x;
    const int NR = NCHUNKS * NST * 48;
    if (u < NR) {
        int dd = (u % 48) * 4;
        int nn = (u / 48) % NST;
        int bc = u / (48 * NST);
        const size_t Q2 = (size_t)NST * DIM;
        size_t so = ((size_t)(bc * NSUB) * NST + nn) * DIM + dd;
        float4 acc = {0.f, 0.f, 0.f, 0.f};
        #pragma unroll
        for (int s = 0; s < NSUB; ++s) {
            float4 v = *(const float4*)(R + so + (size_t)s * Q2);
            acc.x += v.x; acc.y += v.y; acc.z += v.z; acc.w += v.w;
        }
        *(float4*)(Rsum + ((size_t)bc * NST + nn) * DIM + dd) = acc;
    } else if (u < NR + NCHUNKS * 48) {
        int v = u - NR;
        int dd = (v % 48) * 4;
        int bc = v / 48;
        float4 acc = {1.f, 1.f, 1.f, 1.f};
        #pragma unroll
        for (int s = 0; s < NSUB; ++s) {
            float4 dp = *(const float4*)(dprod + (size_t)(bc * NSUB + s) * DIM + dd);
            acc.x *= dp.x; acc.y *= dp.y; acc.z *= dp.z; acc.w *= dp.w;
        }
        *(float4*)(cA + (size_t)bc * DIM + dd) = acc;
    }
}

// ---------------------------------------------------------------------------
// Inter-chunk scan: 16 steps, prefetched
// ---------------------------------------------------------------------------
__global__ __launch_bounds__(256)
void scan_kernel(const float* __restrict__ cA,
                 const float* __restrict__ Rsum,
                 float* __restrict__ prev)
{
    int v = blockIdx.x * 256 + threadIdx.x;
    if (v >= BATCH * NST * 48) return;
    int dd = (v % 48) * 4;
    int nn = (v / 48) % NST;
    int b  = v / (48 * NST);
    int bc0 = b * CPB;
    float4 st = {0.f, 0.f, 0.f, 0.f};
    float4 a_cur = *(const float4*)(cA + (size_t)bc0 * DIM + dd);
    float4 r_cur = *(const float4*)(Rsum + ((size_t)bc0 * NST + nn) * DIM + dd);
    for (int c = 0; c < CPB; ++c) {
        int bc = bc0 + c;
        float4 a_nxt = {0,0,0,0}, r_nxt = {0,0,0,0};
        if (c + 1 < CPB) {
            a_nxt = *(const float4*)(cA + (size_t)(bc + 1) * DIM + dd);
            r_nxt = *(const float4*)(Rsum + ((size_t)(bc + 1) * NST + nn) * DIM + dd);
        }
        *(float4*)(prev + ((size_t)bc * NST + nn) * DIM + dd) = st;
        st.x = fmaf(st.x, a_cur.x, r_cur.x);
        st.y = fmaf(st.y, a_cur.y, r_cur.y);
        st.z = fmaf(st.z, a_cur.z, r_cur.z);
        st.w = fmaf(st.w, a_cur.w, r_cur.w);
        a_cur = a_nxt; r_cur = r_nxt;
    }
}

// ---------------------------------------------------------------------------
// Intra recurrence. H seeded with inline carry scan over earlier sub-chunks.
// Grid (64, 4 subs, 2 g), 192 thr. p_y written bf16 (2 partials).
// ---------------------------------------------------------------------------
__global__ __launch_bounds__(192)
void intra_kernel(const float* __restrict__ xbar,
                  const float* __restrict__ Abar,
                  const float* __restrict__ BC,     // stride 128; B cols 0..63, C 64..127
                  const float* __restrict__ prev,
                  const float* __restrict__ S,
                  const float* __restrict__ dprod,
                  unsigned short* __restrict__ p_y)
{
    int bc = blockIdx.x, s = blockIdx.y, g = blockIdx.z;
    int dd = threadIdx.x;
    int t0 = bc * PCHUNK + s * SUB;
    __shared__ float Bs[SUB][NPG];
    __shared__ float Cs[SUB][NPG];
    {
        int nunits = SUB * NPG / 4;             // 256 per matrix
        for (int idx = threadIdx.x; idx < 2 * nunits; idx += 192) {
            int m = idx >= nunits;
            int q = idx - m * nunits;
            int row = q >> 3, c4 = q & 7;
            const float* src = BC + (size_t)(t0 + row) * 128
                             + (m ? 64 : 0) + g * NPG + c4 * 4;
            float4 v = *(const float4*)src;
            if (m) *(float4*)&Cs[row][c4 * 4] = v;
            else   *(float4*)&Bs[row][c4 * 4] = v;
        }
    }
    float H[NPG] = {}, P[NPG];
    for (int k = 0; k < s; ++k) {
        float dpk = dprod[(size_t)(bc * NSUB + k) * DIM + dd];
        size_t sb = (((size_t)(bc * NSUB + k)) * NST + g * NPG) * DIM + dd;
        #pragma unroll
        for (int j = 0; j < NPG; ++j)
            H[j] = fmaf(H[j], dpk, S[sb + (size_t)j * DIM]);
    }
    #pragma unroll
    for (int j = 0; j < NPG; ++j)
        P[j] = prev[((size_t)bc * NST + g * NPG + j) * DIM + dd];
    __syncthreads();

    float a_cur = Abar[(size_t)t0 * DIM + dd] + 1e-8f;
    float x_cur = xbar[(size_t)t0 * DIM + dd];
    for (int i = 0; i < SUB; ++i) {
        int t = t0 + i;
        float a_nxt = 0.f, x_nxt = 0.f;
        if (i + 1 < SUB) {
            a_nxt = Abar[(size_t)(t + 1) * DIM + dd] + 1e-8f;
            x_nxt = xbar[(size_t)(t + 1) * DIM + dd];
        }
        float ya[4] = {0.f, 0.f, 0.f, 0.f};
        #pragma unroll
        for (int q = 0; q < NPG / 4; ++q) {
            float4 b = *(const float4*)&Bs[i][q * 4];
            float4 c = *(const float4*)&Cs[i][q * 4];
            H[q*4+0] = fmaf(a_cur, H[q*4+0], b.x * x_cur);
            ya[0] = fmaf(c.x, H[q*4+0] + P[q*4+0], ya[0]);
            H[q*4+1] = fmaf(a_cur, H[q*4+1], b.y * x_cur);
            ya[1] = fmaf(c.y, H[q*4+1] + P[q*4+1], ya[1]);
            H[q*4+2] = fmaf(a_cur, H[q*4+2], b.z * x_cur);
            ya[2] = fmaf(c.z, H[q*4+2] + P[q*4+2], ya[2]);
            H[q*4+3] = fmaf(a_cur, H[q*4+3], b.w * x_cur);
            ya[3] = fmaf(c.w, H[q*4+3] + P[q*4+3], ya[3]);
        }
        p_y[((size_t)g * TOK + t) * DIM + dd] = f2bf((ya[0] + ya[1]) + (ya[2] + ya[3]));
        a_cur = a_nxt; x_cur = x_nxt;
    }
}

// y_g = (p_y0 + p_y1) * silu(z)  -> bf16
__global__ __launch_bounds__(256)
void gate_kernel(const unsigned short* __restrict__ p_y,
                 const float* __restrict__ zarr,
                 unsigned short* __restrict__ ygb)
{
    int v = blockIdx.x * 256 + threadIdx.x;
    if (v >= TOK * 48) return;
    int t = v / 48;
    int dd = (v % 48) * 4;
    const size_t Q = (size_t)TOK * DIM;
    size_t off = (size_t)t * DIM + dd;
    ushort4 y0 = *(const ushort4*)(p_y + off);
    ushort4 y1 = *(const ushort4*)(p_y + off + Q);
    float4 z = *(const float4*)(zarr + off);
    ushort4 r;
    r.x = f2bf((bf2f(y0.x) + bf2f(y1.x)) * (z.x / (1.f + expf(-z.x))));
    r.y = f2bf((bf2f(y0.y) + bf2f(y1.y)) * (z.y / (1.f + expf(-z.y))));
    r.z = f2bf((bf2f(y0.z) + bf2f(y1.z)) * (z.z / (1.f + expf(-z.z))));
    r.w = f2bf((bf2f(y0.w) + bf2f(y1.w)) * (z.w / (1.f + expf(-z.w))));
    *(ushort4*)(ygb + off) = r;
}

// ---------------------------------------------------------------------------
extern "C" void kernel_launch(void* const* d_in, const int* in_sizes, int n_in,
                              void* d_out, int out_size, void* d_ws, size_t ws_size,
                              hipStream_t stream)
{
    (void)in_sizes; (void)n_in; (void)out_size; (void)ws_size;
    const float* x     = (const float*)d_in[0];
    const float* A_log = (const float*)d_in[1];
    const float* W_B   = (const float*)d_in[2];
    const float* W_C   = (const float*)d_in[3];
    const float* W_dt  = (const float*)d_in[4];
    const float* b_dt  = (const float*)d_in[5];
    const float* W_xp  = (const float*)d_in[6];
    const float* b_xp  = (const float*)d_in[7];
    const float* W_out = (const float*)d_in[8];
    const float* b_out = (const float*)d_in[9];
    float* out = (float*)d_out;

    char* w = (char*)d_ws;
    auto take = [&](size_t bytes) { char* p = w; w += (bytes + 255) & ~(size_t)255; return p; };
    unsigned short* xb     = (unsigned short*)take((size_t)TOK*DIM*2);
    unsigned short* wxpb   = (unsigned short*)take((size_t)384*DIM*2);
    unsigned short* woutb  = (unsigned short*)take((size_t)DIM*DIM*2);
    unsigned short* wcombb = (unsigned short*)take((size_t)320*DIM*2);
    float*          biasC  = (float*)         take((size_t)320*4);
    float*          xbar   = (float*)         take((size_t)TOK*DIM*4);
    float*          zarr   = (float*)         take((size_t)TOK*DIM*4);
    float*          BC     = (float*)         take((size_t)TOK*128*4);
    float*          Abar   = (float*)         take((size_t)TOK*DIM*4);
    float*          dprod  = (float*)         take((size_t)NCHUNKS*NSUB*DIM*4);
    float*          cAc    = (float*)         take((size_t)NCHUNKS*DIM*4);
    float*          prev   = (float*)         take((size_t)NCHUNKS*NST*DIM*4);
    float*          Rsum   = (float*)         take((size_t)NCHUNKS*NST*DIM*4);
    float*          Sarr   = (float*)         take((size_t)NCHUNKS*NSUB*NST*DIM*4);
    float*          Rarr   = (float*)         take((size_t)NCHUNKS*NSUB*NST*DIM*4);
    unsigned short* p_y    = (unsigned short*)take((size_t)NG*TOK*DIM*2);
    unsigned short* ygb    = (unsigned short*)take((size_t)TOK*DIM*2);

    dim3 blk(256);

    prep_kernel<<<dim3((PREP_N + 255)/256), blk, 0, stream>>>(
        x, W_xp, W_B, W_C, W_dt, W_out, b_xp, b_dt, xb, wxpb, woutb, wcombb, biasC);
    xz_gemm<<<dim3(TOK/256, 384/64), blk, 0, stream>>>(xb, wxpb, b_xp, xbar, zarr);
    bcdt_gemm<<<dim3(TOK/256, 320/64), blk, 0, stream>>>(xb, wcombb, biasC, A_log, BC, Abar);
    state_kernel<<<dim3(NCHUNKS, NSUB, NG), dim3(192), 0, stream>>>(
        xbar, Abar, BC, Sarr, Rarr, dprod);
    reduce_kernel<<<dim3((NCHUNKS*NST*48 + NCHUNKS*48 + 255)/256), blk, 0, stream>>>(
        dprod, Rarr, cAc, Rsum);
    scan_kernel<<<dim3((BATCH*NST*48 + 255)/256), blk, 0, stream>>>(cAc, Rsum, prev);
    intra_kernel<<<dim3(NCHUNKS, NSUB, NG), dim3(192), 0, stream>>>(
        xbar, Abar, BC, prev, Sarr, dprod, p_y);
    gate_kernel<<<dim3((TOK*48 + 255)/256), blk, 0, stream>>>(p_y, zarr, ygb);
    out_gemm<<<dim3(TOK/256, DIM/64), blk, 0, stream>>>(ygb, woutb, b_out, out);
}

// Round 8
// 184.857 us; speedup vs baseline: 1.0228x; 1.0228x over previous
//
#include <hip/hip_runtime.h>
#include <math.h>

// Problem constants: B=4, L=2048, d=192, n=64, chunk=128
#define TOK      8192
#define DIM      192
#define NST      64
#define PCHUNK   128
#define NCHUNKS  64
#define CPB      16
#define BATCH    4
#define SUB      32
#define NSUB     4
#define NG       4      // n-groups  (1024 blocks in state/intra = 12 waves/CU)
#define NPG      16     // n per group

typedef __attribute__((ext_vector_type(8))) short  bf16x8;
typedef __attribute__((ext_vector_type(4))) float  f32x4;

__device__ __forceinline__ unsigned short f2bf(float f) {
    unsigned int u = __float_as_uint(f);
    u += 0x7fff + ((u >> 16) & 1);          // RNE
    return (unsigned short)(u >> 16);
}
__device__ __forceinline__ float bf2f(unsigned short h) {
    return __uint_as_float(((unsigned int)h) << 16);
}

// ---------------------------------------------------------------------------
// Prep: cast x / W_xp / W_out to bf16; build Wcomb = [W_B;W_C;W_dt] @ W_xp_top
// (fp32 accumulate -> bf16) and folded bias biasC[n] = Wrow.b_xp (+ b_dt).
// ---------------------------------------------------------------------------
#define XU      393216                 // TOK*DIM/4
#define WXPU    18432                  // 384*192/4
#define WOUTU   9216                   // 192*192/4
#define CAST_U  (XU + WXPU + WOUTU)
#define WCOMB_N 61440                  // 320*192
#define PREP_N  (CAST_U + WCOMB_N + 320)

__global__ __launch_bounds__(256)
void prep_kernel(const float* __restrict__ x,   const float* __restrict__ Wxp,
                 const float* __restrict__ WB,  const float* __restrict__ WC,
                 const float* __restrict__ Wdt, const float* __restrict__ Wout,
                 const float* __restrict__ b_xp, const float* __restrict__ b_dt,
                 unsigned short* __restrict__ xb,     unsigned short* __restrict__ wxpb,
                 unsigned short* __restrict__ woutb,  unsigned short* __restrict__ wcombb,
                 float* __restrict__ biasC)
{
    int u = blockIdx.x * 256 + threadIdx.x;
    if (u < CAST_U) {
        const float* src; unsigned short* dst; int idx;
        if      (u < XU)          { src = x;    dst = xb;    idx = u; }
        else if (u < XU + WXPU)   { src = Wxp;  dst = wxpb;  idx = u - XU; }
        else                      { src = Wout; dst = woutb; idx = u - XU - WXPU; }
        float4 v = *(const float4*)(src + (size_t)idx * 4);
        ushort4 r; r.x = f2bf(v.x); r.y = f2bf(v.y); r.z = f2bf(v.z); r.w = f2bf(v.w);
        *(ushort4*)(dst + (size_t)idx * 4) = r;
    } else if (u < CAST_U + WCOMB_N) {
        int idx = u - CAST_U;
        int n = idx / DIM, k = idx % DIM;
        const float* wr = (n < 64) ? WB + (size_t)n * DIM
                        : (n < 128) ? WC + (size_t)(n - 64) * DIM
                                    : Wdt + (size_t)(n - 128) * DIM;
        float acc = 0.f;
        for (int j = 0; j < DIM; ++j)
            acc = fmaf(wr[j], Wxp[(size_t)j * DIM + k], acc);
        wcombb[(size_t)n * DIM + k] = f2bf(acc);
    } else if (u < PREP_N) {
        int n = u - CAST_U - WCOMB_N;
        const float* wr = (n < 64) ? WB + (size_t)n * DIM
                        : (n < 128) ? WC + (size_t)(n - 64) * DIM
                                    : Wdt + (size_t)(n - 128) * DIM;
        float acc = 0.f;
        for (int j = 0; j < DIM; ++j)
            acc = fmaf(wr[j], b_xp[j], acc);
        if (n >= 128) acc += b_dt[n - 128];
        biasC[n] = acc;
    }
}

// ---------------------------------------------------------------------------
// MFMA wave-tile: 64x64 of X[M,K] @ W[N,K]^T (bf16 -> fp32)
// ---------------------------------------------------------------------------
__device__ __forceinline__
void mfma_64x64(const unsigned short* __restrict__ X, int ldx,
                const unsigned short* __restrict__ W, int K,
                int m_wave, int n0, int lr, int kg, f32x4 acc[4][4])
{
    for (int k0 = 0; k0 < K; k0 += 32) {
        bf16x8 af[4], bfr[4];
        #pragma unroll
        for (int mi = 0; mi < 4; ++mi)
            af[mi] = *(const bf16x8*)(X + (size_t)(m_wave + mi*16 + lr) * ldx + k0 + kg*8);
        #pragma unroll
        for (int ni = 0; ni < 4; ++ni)
            bfr[ni] = *(const bf16x8*)(W + (size_t)(n0 + ni*16 + lr) * K + k0 + kg*8);
        #pragma unroll
        for (int mi = 0; mi < 4; ++mi)
            #pragma unroll
            for (int ni = 0; ni < 4; ++ni)
                acc[mi][ni] = __builtin_amdgcn_mfma_f32_16x16x32_bf16(
                                  af[mi], bfr[ni], acc[mi][ni], 0, 0, 0);
    }
}

// x @ W_xp^T + b_xp -> xbar fp32 [TOK][192] | zarr fp32 [TOK][192]
__global__ __launch_bounds__(256)
void xz_gemm(const unsigned short* __restrict__ xb,
             const unsigned short* __restrict__ wxpb,
             const float* __restrict__ b_xp,
             float* __restrict__ xbar, float* __restrict__ zarr)
{
    const int lane = threadIdx.x & 63, wave = threadIdx.x >> 6;
    const int m_wave = blockIdx.x * 256 + wave * 64;
    const int n0 = blockIdx.y * 64;
    const int lr = lane & 15, kg = lane >> 4;
    f32x4 acc[4][4] = {};
    mfma_64x64(xb, DIM, wxpb, DIM, m_wave, n0, lr, kg, acc);
    float* dst = (n0 < DIM) ? xbar : zarr;
    int cofs = (n0 < DIM) ? 0 : DIM;
    #pragma unroll
    for (int ni = 0; ni < 4; ++ni) {
        int col = n0 + ni*16 + lr;
        float bias = b_xp[col];
        #pragma unroll
        for (int mi = 0; mi < 4; ++mi)
            #pragma unroll
            for (int r = 0; r < 4; ++r) {
                int row = m_wave + mi*16 + kg*4 + r;
                dst[(size_t)row * DIM + col - cofs] = acc[mi][ni][r] + bias;
            }
    }
}

// x @ Wcomb^T + biasC: cols<128 -> BC fp32 [TOK][128]; cols>=128 -> Abar
__global__ __launch_bounds__(256)
void bcdt_gemm(const unsigned short* __restrict__ xb,
               const unsigned short* __restrict__ wcombb,
               const float* __restrict__ biasC, const float* __restrict__ A_log,
               float* __restrict__ BC, float* __restrict__ Abar)
{
    const int lane = threadIdx.x & 63, wave = threadIdx.x >> 6;
    const int m_wave = blockIdx.x * 256 + wave * 64;
    const int n0 = blockIdx.y * 64;
    const int lr = lane & 15, kg = lane >> 4;
    f32x4 acc[4][4] = {};
    mfma_64x64(xb, DIM, wcombb, DIM, m_wave, n0, lr, kg, acc);
    if (n0 < 128) {
        #pragma unroll
        for (int ni = 0; ni < 4; ++ni) {
            int col = n0 + ni*16 + lr;
            float bias = biasC[col];
            #pragma unroll
            for (int mi = 0; mi < 4; ++mi)
                #pragma unroll
                for (int r = 0; r < 4; ++r) {
                    int row = m_wave + mi*16 + kg*4 + r;
                    BC[(size_t)row * 128 + col] = acc[mi][ni][r] + bias;
                }
        }
    } else {
        #pragma unroll
        for (int ni = 0; ni < 4; ++ni) {
            int col = n0 + ni*16 + lr;
            int c2 = col - 128;
            float bias = biasC[col];
            float Av = -expf(A_log[c2]);
            #pragma unroll
            for (int mi = 0; mi < 4; ++mi)
                #pragma unroll
                for (int r = 0; r < 4; ++r) {
                    int row = m_wave + mi*16 + kg*4 + r;
                    float v = acc[mi][ni][r] + bias;
                    float sp = (v > 20.f) ? v : log1pf(expf(v));
                    Abar[(size_t)row * DIM + c2] = expf(sp * Av);
                }
        }
    }
}

// out = y_g @ W_out^T + b_out  (fp32)
__global__ __launch_bounds__(256)
void out_gemm(const unsigned short* __restrict__ ygb,
              const unsigned short* __restrict__ woutb,
              const float* __restrict__ b_out, float* __restrict__ out)
{
    const int lane = threadIdx.x & 63, wave = threadIdx.x >> 6;
    const int m_wave = blockIdx.x * 256 + wave * 64;
    const int n0 = blockIdx.y * 64;
    const int lr = lane & 15, kg = lane >> 4;
    f32x4 acc[4][4] = {};
    mfma_64x64(ygb, DIM, woutb, DIM, m_wave, n0, lr, kg, acc);
    #pragma unroll
    for (int ni = 0; ni < 4; ++ni) {
        int col = n0 + ni*16 + lr;
        float bias = b_out[col];
        #pragma unroll
        for (int mi = 0; mi < 4; ++mi)
            #pragma unroll
            for (int r = 0; r < 4; ++r) {
                int row = m_wave + mi*16 + kg*4 + r;
                out[(size_t)row * DIM + col] = acc[mi][ni][r] + bias;
            }
    }
}

// ---------------------------------------------------------------------------
// Fused sub-state + chunk-state partial. Grid (64, 4 subs, 4 g), 192 thr.
// S/R stored bf16 (inter-chunk path only; ~0.4% rel err, well in budget).
// ---------------------------------------------------------------------------
__global__ __launch_bounds__(192)
void state_kernel(const float* __restrict__ xbar,
                  const float* __restrict__ Abar,
                  const float* __restrict__ Bm,      // BC, stride 128 (B cols 0..63)
                  unsigned short* __restrict__ S,
                  unsigned short* __restrict__ R,
                  float* __restrict__ dprod)
{
    int bc = blockIdx.x, s = blockIdx.y, g = blockIdx.z;
    int dd = threadIdx.x;
    int t0 = bc * PCHUNK + s * SUB;
    __shared__ float Bs[SUB][NPG];
    if (threadIdx.x < SUB * NPG / 4) {
        int row = threadIdx.x >> 2, c4 = threadIdx.x & 3;
        *(float4*)&Bs[row][c4 * 4] =
            *(const float4*)(Bm + (size_t)(t0 + row) * 128 + g * NPG + c4 * 4);
    }
    __syncthreads();
    float H[NPG] = {}, Rr[NPG] = {};
    float cp = 1.f;
    float a_cur = Abar[(size_t)t0 * DIM + dd] + 1e-8f;
    float x_cur = xbar[(size_t)t0 * DIM + dd];
    for (int i = 0; i < SUB; ++i) {
        float a_nxt = 0.f, x_nxt = 0.f;
        if (i + 1 < SUB) {
            a_nxt = Abar[(size_t)(t0 + i + 1) * DIM + dd] + 1e-8f;
            x_nxt = xbar[(size_t)(t0 + i + 1) * DIM + dd];
        }
        cp *= a_cur;
        float4 b0 = *(const float4*)&Bs[i][0];
        float4 b1 = *(const float4*)&Bs[i][4];
        float4 b2 = *(const float4*)&Bs[i][8];
        float4 b3 = *(const float4*)&Bs[i][12];
        float bb[NPG] = {b0.x,b0.y,b0.z,b0.w, b1.x,b1.y,b1.z,b1.w,
                         b2.x,b2.y,b2.z,b2.w, b3.x,b3.y,b3.z,b3.w};
        #pragma unroll
        for (int j = 0; j < NPG; ++j) {
            float u = bb[j] * x_cur;
            H[j]  = fmaf(a_cur, H[j], u);
            Rr[j] = fmaf(u, a_cur, Rr[j]);
        }
        a_cur = a_nxt; x_cur = x_nxt;
    }
    size_t base = (((size_t)(bc * NSUB + s)) * NST + g * NPG) * DIM + dd;
    #pragma unroll
    for (int j = 0; j < NPG; ++j) {
        S[base + (size_t)j * DIM] = f2bf(H[j]);
        R[base + (size_t)j * DIM] = f2bf(Rr[j]);
    }
    if (g == 0) dprod[(size_t)(bc * PCHUNK / SUB + s) * DIM + dd] = cp;
}

// ---------------------------------------------------------------------------
// Per-chunk reductions: cA[bc,dd] = prod_s dprod ; Rsum[bc,nn,dd] = sum_s R
// ---------------------------------------------------------------------------
__global__ __launch_bounds__(256)
void reduce_kernel(const float* __restrict__ dprod,
                   const unsigned short* __restrict__ R,
                   float* __restrict__ cA,
                   float* __restrict__ Rsum)
{
    int u = blockIdx.x * 256 + threadIdx.x;
    const int NR = NCHUNKS * NST * 48;
    if (u < NR) {
        int dd = (u % 48) * 4;
        int nn = (u / 48) % NST;
        int bc = u / (48 * NST);
        const size_t Q2 = (size_t)NST * DIM;
        size_t so = ((size_t)(bc * NSUB) * NST + nn) * DIM + dd;
        float4 acc = {0.f, 0.f, 0.f, 0.f};
        #pragma unroll
        for (int s = 0; s < NSUB; ++s) {
            ushort4 v = *(const ushort4*)(R + so + (size_t)s * Q2);
            acc.x += bf2f(v.x); acc.y += bf2f(v.y);
            acc.z += bf2f(v.z); acc.w += bf2f(v.w);
        }
        *(float4*)(Rsum + ((size_t)bc * NST + nn) * DIM + dd) = acc;
    } else if (u < NR + NCHUNKS * 48) {
        int v = u - NR;
        int dd = (v % 48) * 4;
        int bc = v / 48;
        float4 acc = {1.f, 1.f, 1.f, 1.f};
        #pragma unroll
        for (int s = 0; s < NSUB; ++s) {
            float4 dp = *(const float4*)(dprod + (size_t)(bc * NSUB + s) * DIM + dd);
            acc.x *= dp.x; acc.y *= dp.y; acc.z *= dp.z; acc.w *= dp.w;
        }
        *(float4*)(cA + (size_t)bc * DIM + dd) = acc;
    }
}

// ---------------------------------------------------------------------------
// Inter-chunk scan: 16 steps, prefetched
// ---------------------------------------------------------------------------
__global__ __launch_bounds__(256)
void scan_kernel(const float* __restrict__ cA,
                 const float* __restrict__ Rsum,
                 float* __restrict__ prev)
{
    int v = blockIdx.x * 256 + threadIdx.x;
    if (v >= BATCH * NST * 48) return;
    int dd = (v % 48) * 4;
    int nn = (v / 48) % NST;
    int b  = v / (48 * NST);
    int bc0 = b * CPB;
    float4 st = {0.f, 0.f, 0.f, 0.f};
    float4 a_cur = *(const float4*)(cA + (size_t)bc0 * DIM + dd);
    float4 r_cur = *(const float4*)(Rsum + ((size_t)bc0 * NST + nn) * DIM + dd);
    for (int c = 0; c < CPB; ++c) {
        int bc = bc0 + c;
        float4 a_nxt = {0,0,0,0}, r_nxt = {0,0,0,0};
        if (c + 1 < CPB) {
            a_nxt = *(const float4*)(cA + (size_t)(bc + 1) * DIM + dd);
            r_nxt = *(const float4*)(Rsum + ((size_t)(bc + 1) * NST + nn) * DIM + dd);
        }
        *(float4*)(prev + ((size_t)bc * NST + nn) * DIM + dd) = st;
        st.x = fmaf(st.x, a_cur.x, r_cur.x);
        st.y = fmaf(st.y, a_cur.y, r_cur.y);
        st.z = fmaf(st.z, a_cur.z, r_cur.z);
        st.w = fmaf(st.w, a_cur.w, r_cur.w);
        a_cur = a_nxt; r_cur = r_nxt;
    }
}

// ---------------------------------------------------------------------------
// Intra recurrence. H seeded with inline carry scan over earlier sub-chunks.
// Grid (64, 4 subs, 4 g), 192 thr. p_y written bf16 (4 partials).
// ---------------------------------------------------------------------------
__global__ __launch_bounds__(192)
void intra_kernel(const float* __restrict__ xbar,
                  const float* __restrict__ Abar,
                  const float* __restrict__ BC,     // stride 128; B 0..63, C 64..127
                  const float* __restrict__ prev,
                  const unsigned short* __restrict__ S,
                  const float* __restrict__ dprod,
                  unsigned short* __restrict__ p_y)
{
    int bc = blockIdx.x, s = blockIdx.y, g = blockIdx.z;
    int dd = threadIdx.x;
    int t0 = bc * PCHUNK + s * SUB;
    __shared__ float Bs[SUB][NPG];
    __shared__ float Cs[SUB][NPG];
    {
        int nunits = SUB * NPG / 4;             // 128 per matrix
        for (int idx = threadIdx.x; idx < 2 * nunits; idx += 192) {
            int m = idx >= nunits;
            int q = idx - m * nunits;
            int row = q >> 2, c4 = q & 3;
            const float* src = BC + (size_t)(t0 + row) * 128
                             + (m ? 64 : 0) + g * NPG + c4 * 4;
            float4 v = *(const float4*)src;
            if (m) *(float4*)&Cs[row][c4 * 4] = v;
            else   *(float4*)&Bs[row][c4 * 4] = v;
        }
    }
    float H[NPG] = {}, P[NPG];
    for (int k = 0; k < s; ++k) {
        float dpk = dprod[(size_t)(bc * NSUB + k) * DIM + dd];
        size_t sb = (((size_t)(bc * NSUB + k)) * NST + g * NPG) * DIM + dd;
        #pragma unroll
        for (int j = 0; j < NPG; ++j)
            H[j] = fmaf(H[j], dpk, bf2f(S[sb + (size_t)j * DIM]));
    }
    #pragma unroll
    for (int j = 0; j < NPG; ++j)
        P[j] = prev[((size_t)bc * NST + g * NPG + j) * DIM + dd];
    __syncthreads();

    float a_cur = Abar[(size_t)t0 * DIM + dd] + 1e-8f;
    float x_cur = xbar[(size_t)t0 * DIM + dd];
    for (int i = 0; i < SUB; ++i) {
        int t = t0 + i;
        float a_nxt = 0.f, x_nxt = 0.f;
        if (i + 1 < SUB) {
            a_nxt = Abar[(size_t)(t + 1) * DIM + dd] + 1e-8f;
            x_nxt = xbar[(size_t)(t + 1) * DIM + dd];
        }
        float4 b0 = *(const float4*)&Bs[i][0];
        float4 b1 = *(const float4*)&Bs[i][4];
        float4 b2 = *(const float4*)&Bs[i][8];
        float4 b3 = *(const float4*)&Bs[i][12];
        float4 c0 = *(const float4*)&Cs[i][0];
        float4 c1 = *(const float4*)&Cs[i][4];
        float4 c2 = *(const float4*)&Cs[i][8];
        float4 c3 = *(const float4*)&Cs[i][12];
        float bb[NPG] = {b0.x,b0.y,b0.z,b0.w, b1.x,b1.y,b1.z,b1.w,
                         b2.x,b2.y,b2.z,b2.w, b3.x,b3.y,b3.z,b3.w};
        float cc[NPG] = {c0.x,c0.y,c0.z,c0.w, c1.x,c1.y,c1.z,c1.w,
                         c2.x,c2.y,c2.z,c2.w, c3.x,c3.y,c3.z,c3.w};
        float ya[4] = {0.f, 0.f, 0.f, 0.f};
        #pragma unroll
        for (int j = 0; j < NPG; ++j) {
            H[j] = fmaf(a_cur, H[j], bb[j] * x_cur);
            ya[j & 3] = fmaf(cc[j], H[j] + P[j], ya[j & 3]);
        }
        p_y[((size_t)g * TOK + t) * DIM + dd] = f2bf((ya[0] + ya[1]) + (ya[2] + ya[3]));
        a_cur = a_nxt; x_cur = x_nxt;
    }
}

// y_g = (sum of 4 bf16 partials) * silu(z)  -> bf16
__global__ __launch_bounds__(256)
void gate_kernel(const unsigned short* __restrict__ p_y,
                 const float* __restrict__ zarr,
                 unsigned short* __restrict__ ygb)
{
    int v = blockIdx.x * 256 + threadIdx.x;
    if (v >= TOK * 48) return;
    int t = v / 48;
    int dd = (v % 48) * 4;
    const size_t Q = (size_t)TOK * DIM;
    size_t off = (size_t)t * DIM + dd;
    float acc[4] = {0.f, 0.f, 0.f, 0.f};
    #pragma unroll
    for (int gidx = 0; gidx < NG; ++gidx) {
        ushort4 y = *(const ushort4*)(p_y + off + (size_t)gidx * Q);
        acc[0] += bf2f(y.x); acc[1] += bf2f(y.y);
        acc[2] += bf2f(y.z); acc[3] += bf2f(y.w);
    }
    float4 z = *(const float4*)(zarr + off);
    ushort4 r;
    r.x = f2bf(acc[0] * (z.x / (1.f + expf(-z.x))));
    r.y = f2bf(acc[1] * (z.y / (1.f + expf(-z.y))));
    r.z = f2bf(acc[2] * (z.z / (1.f + expf(-z.z))));
    r.w = f2bf(acc[3] * (z.w / (1.f + expf(-z.w))));
    *(ushort4*)(ygb + off) = r;
}

// ---------------------------------------------------------------------------
extern "C" void kernel_launch(void* const* d_in, const int* in_sizes, int n_in,
                              void* d_out, int out_size, void* d_ws, size_t ws_size,
                              hipStream_t stream)
{
    (void)in_sizes; (void)n_in; (void)out_size; (void)ws_size;
    const float* x     = (const float*)d_in[0];
    const float* A_log = (const float*)d_in[1];
    const float* W_B   = (const float*)d_in[2];
    const float* W_C   = (const float*)d_in[3];
    const float* W_dt  = (const float*)d_in[4];
    const float* b_dt  = (const float*)d_in[5];
    const float* W_xp  = (const float*)d_in[6];
    const float* b_xp  = (const float*)d_in[7];
    const float* W_out = (const float*)d_in[8];
    const float* b_out = (const float*)d_in[9];
    float* out = (float*)d_out;

    char* w = (char*)d_ws;
    auto take = [&](size_t bytes) { char* p = w; w += (bytes + 255) & ~(size_t)255; return p; };
    unsigned short* xb     = (unsigned short*)take((size_t)TOK*DIM*2);
    unsigned short* wxpb   = (unsigned short*)take((size_t)384*DIM*2);
    unsigned short* woutb  = (unsigned short*)take((size_t)DIM*DIM*2);
    unsigned short* wcombb = (unsigned short*)take((size_t)320*DIM*2);
    float*          biasC  = (float*)         take((size_t)320*4);
    float*          xbar   = (float*)         take((size_t)TOK*DIM*4);
    float*          zarr   = (float*)         take((size_t)TOK*DIM*4);
    float*          BC     = (float*)         take((size_t)TOK*128*4);
    float*          Abar   = (float*)         take((size_t)TOK*DIM*4);
    float*          dprod  = (float*)         take((size_t)NCHUNKS*NSUB*DIM*4);
    float*          cAc    = (float*)         take((size_t)NCHUNKS*DIM*4);
    float*          prev   = (float*)         take((size_t)NCHUNKS*NST*DIM*4);
    float*          Rsum   = (float*)         take((size_t)NCHUNKS*NST*DIM*4);
    unsigned short* Sarr   = (unsigned short*)take((size_t)NCHUNKS*NSUB*NST*DIM*2);
    unsigned short* Rarr   = (unsigned short*)take((size_t)NCHUNKS*NSUB*NST*DIM*2);
    unsigned short* p_y    = (unsigned short*)take((size_t)NG*TOK*DIM*2);
    unsigned short* ygb    = (unsigned short*)take((size_t)TOK*DIM*2);

    dim3 blk(256);

    prep_kernel<<<dim3((PREP_N + 255)/256), blk, 0, stream>>>(
        x, W_xp, W_B, W_C, W_dt, W_out, b_xp, b_dt, xb, wxpb, woutb, wcombb, biasC);
    xz_gemm<<<dim3(TOK/256, 384/64), blk, 0, stream>>>(xb, wxpb, b_xp, xbar, zarr);
    bcdt_gemm<<<dim3(TOK/256, 320/64), blk, 0, stream>>>(xb, wcombb, biasC, A_log, BC, Abar);
    state_kernel<<<dim3(NCHUNKS, NSUB, NG), dim3(192), 0, stream>>>(
        xbar, Abar, BC, Sarr, Rarr, dprod);
    reduce_kernel<<<dim3((NCHUNKS*NST*48 + NCHUNKS*48 + 255)/256), blk, 0, stream>>>(
        dprod, Rarr, cAc, Rsum);
    scan_kernel<<<dim3((BATCH*NST*48 + 255)/256), blk, 0, stream>>>(cAc, Rsum, prev);
    intra_kernel<<<dim3(NCHUNKS, NSUB, NG), dim3(192), 0, stream>>>(
        xbar, Abar, BC, prev, Sarr, dprod, p_y);
    gate_kernel<<<dim3((TOK*48 + 255)/256), blk, 0, stream>>>(p_y, zarr, ygb);
    out_gemm<<<dim3(TOK/256, DIM/64), blk, 0, stream>>>(ygb, woutb, b_out, out);
}